// Round 7
// baseline (46.695 us; speedup 1.0000x reference)
//
#include <hip/hip_runtime.h>
#include <hip/hip_fp16.h>

#define NR 700
#define KK 250
#define HID 32

typedef unsigned int uint32;

__device__ __forceinline__ __half2 u2h(uint32 u) { return __builtin_bit_cast(__half2, u); }
__device__ __forceinline__ uint32 h2u(__half2 h) { return __builtin_bit_cast(uint32, h); }

__device__ __forceinline__ __half2 pk_min(__half2 a, __half2 b) {
    uint32 ua = h2u(a), ub = h2u(b), ud;
    asm("v_pk_min_f16 %0, %1, %2" : "=v"(ud) : "v"(ua), "v"(ub));
    return u2h(ud);
}
__device__ __forceinline__ __half2 pk_max(__half2 a, __half2 b) {
    uint32 ua = h2u(a), ub = h2u(b), ud;
    asm("v_pk_max_f16 %0, %1, %2" : "=v"(ud) : "v"(ua), "v"(ub));
    return u2h(ud);
}

// packed exp2: 2^s per fp16 half, s clamped to [-14, 12].
// magic-add rounds s to n (RNE); poly on f in [-0.5,0.5]; 2^n bits spliced from y's bit pattern.
__device__ __forceinline__ __half2 exp2pk(__half2 s2, __half2 MAG, __half2 SLO, __half2 SHI,
                                          __half2 C3, __half2 C2, __half2 C1, __half2 C0) {
    s2 = pk_max(pk_min(s2, SHI), SLO);
    __half2 y = __hadd2(s2, MAG);          // bits(y) per half = 0x6600 + n
    __half2 n = __hsub2(y, MAG);
    __half2 f = __hsub2(s2, n);
    __half2 p = __hfma2(__hfma2(__hfma2(C3, f, C2), f, C1), f, C0);
    uint32 u = h2u(y);
    uint32 e = ((u + 0x000F000Fu) << 10) & 0xFC00FC00u;   // per half: (n+15)<<10 = bits of 2^n
    return __hmul2(p, u2h(e));
}

__device__ __forceinline__ void compute_weights(
    int wt, int l,
    const float* __restrict__ Wq, const float* __restrict__ bq,
    const float* __restrict__ Wk, const float* __restrict__ bk,
    const float* __restrict__ Wv, const float* __restrict__ bv,
    float (*Msh)[7], float* wsh, float* wvsh, float SC2)
{
    const float* wq = Wq + l * 7 * HID;
    const float* wk = Wk + l * 7 * HID;
    if (wt < 49) {
        int c = wt / 7, cp = wt % 7;
        float s = 0.f;
        #pragma unroll 8
        for (int d = 0; d < HID; ++d) s = fmaf(wq[c * HID + d], wk[cp * HID + d], s);
        Msh[c][cp] = s * SC2;
    } else if (wt < 56) {
        int cp = wt - 49;
        float s = 0.f;
        #pragma unroll 8
        for (int d = 0; d < HID; ++d) s = fmaf(bq[l * HID + d], wk[cp * HID + d], s);
        wsh[cp] = s * SC2;
    } else if (wt < 63) {
        wvsh[wt - 56] = Wv[l * 7 + (wt - 56)];
    } else if (wt == 63) {
        wvsh[7] = bv[l];
    }
}

// 512 threads = 8 waves. Thread: 4 query rows (slot+64k) as 2 fp16 pairs x 1/8 of j.
__global__ __launch_bounds__(512, 4) void mlra_kernel(
    const float* __restrict__ power,
    const int*   __restrict__ ele_idx,
    const int*   __restrict__ azi_idx,
    const float* __restrict__ ele_emb,
    const float* __restrict__ azi_emb,
    const float* __restrict__ Wq,
    const float* __restrict__ bq,
    const float* __restrict__ Wk,
    const float* __restrict__ bk,
    const float* __restrict__ Wv,
    const float* __restrict__ bv,
    float* __restrict__ out)
{
    __shared__ uint4  hd4[512];        // row r: hd4[2r..2r+1] = 8 u32, each (h_c,h_c) fp16-dup; slot 7 = (v,v)
    __shared__ float  hrowf[256][9];   // fp32 h rows for t-phase (stride 9 spreads banks)
    __shared__ float  ps[8][256];      // [j-split][row] partial sum-exp (fp32)
    __shared__ float  po[8][256];      // [j-split][row] partial sum-exp*v (fp32)
    __shared__ float  Msh[7][7];
    __shared__ float  wsh[7];
    __shared__ float  wvsh[8];

    uint32* hdU = reinterpret_cast<uint32*>(hd4);

    const int r    = blockIdx.x;
    const int tid  = threadIdx.x;
    const int slot = tid & 63;
    const int js   = tid >> 6;    // j-split 0..7 == wave id (wave-uniform)

    const float SC2 = 0.17677669529663687f * 1.4426950408889634f;

    // ---- build h rows: fp32 copy + fp16-dup copy; pads (250..255) zero ----
    if (tid < 256) {
        float hv[8];
        if (tid < KK) {
            int g = r * KK + tid;
            hv[0] = power[g];
            int ei = ele_idx[g];
            int ai = azi_idx[g];
            hv[1] = ele_emb[ei * 3 + 0];
            hv[2] = ele_emb[ei * 3 + 1];
            hv[3] = ele_emb[ei * 3 + 2];
            hv[4] = azi_emb[ai * 3 + 0];
            hv[5] = azi_emb[ai * 3 + 1];
            hv[6] = azi_emb[ai * 3 + 2];
            hv[7] = 0.f;
        } else {
            #pragma unroll
            for (int c = 0; c < 8; ++c) hv[c] = 0.f;
        }
        #pragma unroll
        for (int c = 0; c < 7; ++c) hrowf[tid][c] = hv[c];
        #pragma unroll
        for (int c = 0; c < 8; ++c) {
            uint32 b = (uint32)__half_as_ushort(__float2half_rn(hv[c]));
            hdU[tid * 8 + c] = b | (b << 16);
        }
    }
    if (js == 1) compute_weights(slot, 0, Wq, bq, Wk, bk, Wv, bv, Msh, wsh, wvsh, SC2);
    __syncthreads();   // (a) h + weights(0) ready

    const __half2 MAG = u2h(0x66006600u);
    const __half2 SLO = __float2half2_rn(-14.0f);
    const __half2 SHI = __float2half2_rn(12.0f);
    const __half2 C3  = __float2half2_rn(0.0555041f);
    const __half2 C2  = __float2half2_rn(0.2402265f);
    const __half2 C1  = __float2half2_rn(0.6931472f);
    const __half2 C0  = __float2half2_rn(1.0f);
    const __half2 Z2  = __float2half2_rn(0.0f);

    float xout[4] = {0.f, 0.f, 0.f, 0.f};

    for (int l = 0; l < 2; ++l) {
        // ---- t-phase (fp32), pack into fp16 pairs; js==0 writes v ----
        float tt[4][7];
        #pragma unroll
        for (int k = 0; k < 4; ++k) {
            const int row = slot + 64 * k;
            float hv[7];
            #pragma unroll
            for (int c = 0; c < 7; ++c) hv[c] = hrowf[row][c];
            #pragma unroll
            for (int cp = 0; cp < 7; ++cp) {
                float s = wsh[cp];
                #pragma unroll
                for (int c = 0; c < 7; ++c) s = fmaf(hv[c], Msh[c][cp], s);
                tt[k][cp] = s;
            }
            if (js == 0 && row < KK) {
                float v = wvsh[7];
                #pragma unroll
                for (int c = 0; c < 7; ++c) v = fmaf(hv[c], wvsh[c], v);
                uint32 b = (uint32)__half_as_ushort(__float2half_rn(v));
                hdU[row * 8 + 7] = b | (b << 16);
            }
        }
        __half2 tA[7], tB[7];
        #pragma unroll
        for (int c = 0; c < 7; ++c) {
            tA[c] = __halves2half2(__float2half_rn(tt[0][c]), __float2half_rn(tt[1][c]));
            tB[c] = __halves2half2(__float2half_rn(tt[2][c]), __float2half_rn(tt[3][c]));
        }
        __syncthreads();   // (b) v visible

        // ---- inner loop: 32 j's per wave, fp16-packed; flush partials to fp32 every 8 ----
        float ssf[4] = {0.f, 0.f, 0.f, 0.f};
        float oof[4] = {0.f, 0.f, 0.f, 0.f};
        #pragma unroll
        for (int ot = 0; ot < 4; ++ot) {
            __half2 sA = Z2, sB = Z2, oA = Z2, oB = Z2;
            #pragma unroll
            for (int ii = 0; ii < 8; ++ii) {
                const int j = js + (ot << 6) + (ii << 3);
                uint4 ua = hd4[2 * j];        // broadcast (js wave-uniform)
                uint4 ub = hd4[2 * j + 1];
                __half2 scA = __hfma2(u2h(ub.z), tA[6],
                              __hfma2(u2h(ub.y), tA[5],
                              __hfma2(u2h(ub.x), tA[4],
                              __hfma2(u2h(ua.w), tA[3],
                              __hfma2(u2h(ua.z), tA[2],
                              __hfma2(u2h(ua.y), tA[1],
                              __hmul2(u2h(ua.x), tA[0])))))));
                __half2 scB = __hfma2(u2h(ub.z), tB[6],
                              __hfma2(u2h(ub.y), tB[5],
                              __hfma2(u2h(ub.x), tB[4],
                              __hfma2(u2h(ua.w), tB[3],
                              __hfma2(u2h(ua.z), tB[2],
                              __hfma2(u2h(ua.y), tB[1],
                              __hmul2(u2h(ua.x), tB[0])))))));
                __half2 pA = exp2pk(scA, MAG, SLO, SHI, C3, C2, C1, C0);
                __half2 pB = exp2pk(scB, MAG, SLO, SHI, C3, C2, C1, C0);
                __half2 v2 = u2h(ub.w);
                sA = __hadd2(sA, pA); oA = __hfma2(pA, v2, oA);
                sB = __hadd2(sB, pB); oB = __hfma2(pB, v2, oB);
            }
            ssf[0] += __low2float(sA);  ssf[1] += __high2float(sA);
            ssf[2] += __low2float(sB);  ssf[3] += __high2float(sB);
            oof[0] += __low2float(oA);  oof[1] += __high2float(oA);
            oof[2] += __low2float(oB);  oof[3] += __high2float(oB);
        }
        // pad correction: js>=2 visited exactly one padded j (score=0 -> p=1, v=0)
        const float corr = (js >= 2) ? 1.0f : 0.0f;
        #pragma unroll
        for (int k = 0; k < 4; ++k) {
            const int row = slot + 64 * k;
            ps[js][row] = ssf[k] - corr;
            po[js][row] = oof[k];
        }
        __syncthreads();   // (c) partials ready

        // ---- wave 0: combine + finalize; wave 1: next layer's weights ----
        if (js == 0) {
            #pragma unroll
            for (int k = 0; k < 4; ++k) {
                const int row = slot + 64 * k;
                float s = ((ps[0][row] + ps[1][row]) + (ps[2][row] + ps[3][row]))
                        + ((ps[4][row] + ps[5][row]) + (ps[6][row] + ps[7][row]));
                float o = ((po[0][row] + po[1][row]) + (po[2][row] + po[3][row]))
                        + ((po[4][row] + po[5][row]) + (po[6][row] + po[7][row]));
                float x = o / s;
                xout[k] = x;
                if (l == 0 && row < KK) {
                    hrowf[row][0] = x;   // exact fp32 for layer-1 t-phase
                    uint32 b = (uint32)__half_as_ushort(__float2half_rn(x));
                    hdU[row * 8 + 0] = b | (b << 16);
                }
            }
        } else if (js == 1 && l == 0) {
            compute_weights(slot, 1, Wq, bq, Wk, bk, Wv, bv, Msh, wsh, wvsh, SC2);
        }
        __syncthreads();   // (a') x-update + weights(l+1) published
    }

    if (js == 0) {
        #pragma unroll
        for (int k = 0; k < 4; ++k) {
            const int row = slot + 64 * k;
            if (row < KK) out[r * KK + row] = xout[k];
        }
    }
}

extern "C" void kernel_launch(void* const* d_in, const int* in_sizes, int n_in,
                              void* d_out, int out_size, void* d_ws, size_t ws_size,
                              hipStream_t stream) {
    const float* power   = (const float*)d_in[0];
    const int*   ele     = (const int*)d_in[1];
    const int*   azi     = (const int*)d_in[2];
    const float* ele_emb = (const float*)d_in[3];
    const float* azi_emb = (const float*)d_in[4];
    const float* Wq      = (const float*)d_in[5];
    const float* bq      = (const float*)d_in[6];
    const float* Wk      = (const float*)d_in[7];
    const float* bk      = (const float*)d_in[8];
    const float* Wv      = (const float*)d_in[9];
    const float* bv      = (const float*)d_in[10];
    float* outp = (float*)d_out;

    hipLaunchKernelGGL(mlra_kernel, dim3(NR), dim3(512), 0, stream,
                       power, ele, azi, ele_emb, azi_emb, Wq, bq, Wk, bk, Wv, bv, outp);
}

// Round 8
// 37.000 us; speedup vs baseline: 1.2620x; 1.2620x over previous
//
#include <hip/hip_runtime.h>
#include <hip/hip_fp16.h>

#define NR 700
#define KK 250
#define HID 32

typedef unsigned int uint32;
typedef _Float16 hpair __attribute__((ext_vector_type(2)));

#if __has_builtin(__builtin_amdgcn_fdot2)
#define FDOT2(a, b, c) __builtin_amdgcn_fdot2((a), (b), (c), false)
#else
#define FDOT2(a, b, c) fmaf((float)(a).x, (float)(b).x, fmaf((float)(a).y, (float)(b).y, (c)))
#endif

#if __has_builtin(__builtin_amdgcn_exp2f)
#define EXP2F(x) __builtin_amdgcn_exp2f(x)
#else
#define EXP2F(x) exp2f(x)
#endif

__device__ __forceinline__ hpair u2p(uint32 u) { return __builtin_bit_cast(hpair, u); }
__device__ __forceinline__ uint32 packh2(float lo, float hi) {
    hpair p; p.x = (_Float16)lo; p.y = (_Float16)hi;
    return __builtin_bit_cast(uint32, p);
}

__device__ __forceinline__ void compute_weights(
    int wt, int l,
    const float* __restrict__ Wq, const float* __restrict__ bq,
    const float* __restrict__ Wk,
    const float* __restrict__ Wv, const float* __restrict__ bv,
    float (*Msh)[7], float* wsh, float* wvsh, float SC2)
{
    const float* wq = Wq + l * 7 * HID;
    const float* wk = Wk + l * 7 * HID;
    if (wt < 49) {
        int c = wt / 7, cp = wt % 7;
        float s = 0.f;
        #pragma unroll 8
        for (int d = 0; d < HID; ++d) s = fmaf(wq[c * HID + d], wk[cp * HID + d], s);
        Msh[c][cp] = s * SC2;
    } else if (wt < 56) {
        int cp = wt - 49;
        float s = 0.f;
        #pragma unroll 8
        for (int d = 0; d < HID; ++d) s = fmaf(bq[l * HID + d], wk[cp * HID + d], s);
        wsh[cp] = s * SC2;
    } else if (wt < 63) {
        wvsh[wt - 56] = Wv[l * 7 + (wt - 56)];
    } else if (wt == 63) {
        wvsh[7] = bv[l];
    }
}

// 512 threads = 8 waves. Lane-pair owns one query row: row = tid>>1, jpar = tid&1.
// Each thread privately accumulates its j-parity half; combine = one shfl_xor.
// No cross-wave reduction, no serial combine phase, 5 barriers total.
__global__ __launch_bounds__(512, 4) void mlra_kernel(
    const float* __restrict__ power,
    const int*   __restrict__ ele_idx,
    const int*   __restrict__ azi_idx,
    const float* __restrict__ ele_emb,
    const float* __restrict__ azi_emb,
    const float* __restrict__ Wq,
    const float* __restrict__ bq,
    const float* __restrict__ Wk,
    const float* __restrict__ bk,
    const float* __restrict__ Wv,
    const float* __restrict__ bv,
    float* __restrict__ out)
{
    __shared__ uint4 hh[256];        // 8 fp16 per row: (h0,h1)(h2,h3)(h4,h5)(h6,0); pads zero
    __shared__ float hrowf[256][9];  // fp32 h rows for t-phase (stride 9 -> conflict-free)
    __shared__ float vsh[256];       // v per row, fp32; pads 0
    __shared__ float Msh[2][7][7];   // both layers' folded Wq Wk^T, prologue-computed
    __shared__ float wsh[2][7];
    __shared__ float wvsh[2][8];

    const int r    = blockIdx.x;
    const int tid  = threadIdx.x;
    const int row  = tid >> 1;
    const int jpar = tid & 1;

    const float SC2 = 0.17677669529663687f * 1.4426950408889634f;

    // ---- prologue: h build (threads 0-255) || both layers' weights (waves 4,5) ----
    if (tid < 256) {
        float hv[8];
        if (tid < KK) {
            int g = r * KK + tid;
            hv[0] = power[g];
            int ei = ele_idx[g];
            int ai = azi_idx[g];
            hv[1] = ele_emb[ei * 3 + 0];
            hv[2] = ele_emb[ei * 3 + 1];
            hv[3] = ele_emb[ei * 3 + 2];
            hv[4] = azi_emb[ai * 3 + 0];
            hv[5] = azi_emb[ai * 3 + 1];
            hv[6] = azi_emb[ai * 3 + 2];
            hv[7] = 0.f;
        } else {
            #pragma unroll
            for (int c = 0; c < 8; ++c) hv[c] = 0.f;
        }
        #pragma unroll
        for (int c = 0; c < 7; ++c) hrowf[tid][c] = hv[c];
        uint4 u;
        u.x = packh2(hv[0], hv[1]);
        u.y = packh2(hv[2], hv[3]);
        u.z = packh2(hv[4], hv[5]);
        u.w = packh2(hv[6], 0.f);
        hh[tid] = u;
        vsh[tid] = 0.f;
    } else if (tid < 384) {
        int l = (tid - 256) >> 6;   // wave 4 -> layer 0, wave 5 -> layer 1
        compute_weights(tid & 63, l, Wq, bq, Wk, Wv, bv, Msh[l], wsh[l], wvsh[l], SC2);
    }
    __syncthreads();   // (1) h + both layers' weights ready

    float xval = 0.f;

    for (int l = 0; l < 2; ++l) {
        // ---- t-phase: one row per lane-pair (duplicated across the pair) ----
        float hv[7];
        #pragma unroll
        for (int c = 0; c < 7; ++c) hv[c] = hrowf[row][c];
        float tt[8];
        #pragma unroll
        for (int cp = 0; cp < 7; ++cp) {
            float s = wsh[l][cp];
            #pragma unroll
            for (int c = 0; c < 7; ++c) s = fmaf(hv[c], Msh[l][c][cp], s);
            tt[cp] = s;
        }
        tt[7] = 0.f;
        hpair t0 = u2p(packh2(tt[0], tt[1]));
        hpair t1 = u2p(packh2(tt[2], tt[3]));
        hpair t2 = u2p(packh2(tt[4], tt[5]));
        hpair t3 = u2p(packh2(tt[6], 0.f));
        if (jpar == 0 && row < KK) {
            float v = wvsh[l][7];
            #pragma unroll
            for (int c = 0; c < 7; ++c) v = fmaf(hv[c], wvsh[l][c], v);
            vsh[row] = v;
        }
        __syncthreads();   // (2/5) v ready

        // ---- inner: this thread's j-parity half, 128 iters, fully private ----
        float ss = 0.f, oo = 0.f;
        #pragma unroll 8
        for (int it = 0; it < 128; ++it) {
            const int j = (it << 1) | jpar;
            uint4 ua = hh[j];          // 2 distinct addrs per wave -> broadcast-merged
            float vj = vsh[j];
            float sc = FDOT2(u2p(ua.x), t0,
                       FDOT2(u2p(ua.y), t1,
                       FDOT2(u2p(ua.z), t2,
                       FDOT2(u2p(ua.w), t3, 0.f))));
            float p = EXP2F(sc);
            ss += p;
            oo = fmaf(p, vj, oo);
        }
        // pads (250..255): each parity visits exactly 3, score=0 -> p=1, v=0
        ss -= 3.0f;
        float sst = ss + __shfl_xor(ss, 1);
        float oot = oo + __shfl_xor(oo, 1);
        xval = oot / sst;

        if (l == 0) {
            __syncthreads();   // (3) all inner reads of hh/vsh done
            if (jpar == 0 && row < KK) {
                hrowf[row][0] = xval;                          // exact fp32 for L1 t-phase
                reinterpret_cast<uint32*>(hh)[row * 4 + 0] = packh2(xval, hv[1]);
            }
            __syncthreads();   // (4) x-update published
        }
    }

    if (jpar == 0 && row < KK) out[r * KK + row] = xval;
}

extern "C" void kernel_launch(void* const* d_in, const int* in_sizes, int n_in,
                              void* d_out, int out_size, void* d_ws, size_t ws_size,
                              hipStream_t stream) {
    const float* power   = (const float*)d_in[0];
    const int*   ele     = (const int*)d_in[1];
    const int*   azi     = (const int*)d_in[2];
    const float* ele_emb = (const float*)d_in[3];
    const float* azi_emb = (const float*)d_in[4];
    const float* Wq      = (const float*)d_in[5];
    const float* bq      = (const float*)d_in[6];
    const float* Wk      = (const float*)d_in[7];
    const float* bk      = (const float*)d_in[8];
    const float* Wv      = (const float*)d_in[9];
    const float* bv      = (const float*)d_in[10];
    float* outp = (float*)d_out;
    (void)bk;

    hipLaunchKernelGGL(mlra_kernel, dim3(NR), dim3(512), 0, stream,
                       power, ele, azi, ele_emb, azi_emb, Wq, bq, Wk, bk, Wv, bv, outp);
}

// Round 9
// 36.242 us; speedup vs baseline: 1.2884x; 1.0209x over previous
//
#include <hip/hip_runtime.h>
#include <hip/hip_fp16.h>

#define NR 700
#define KK 250
#define HID 32

typedef unsigned int uint32;
typedef _Float16 hpair __attribute__((ext_vector_type(2)));

#if __has_builtin(__builtin_amdgcn_fdot2)
#define FDOT2(a, b, c) __builtin_amdgcn_fdot2((a), (b), (c), false)
#else
#define FDOT2(a, b, c) fmaf((float)(a).x, (float)(b).x, fmaf((float)(a).y, (float)(b).y, (c)))
#endif

#if __has_builtin(__builtin_amdgcn_exp2f)
#define EXP2F(x) __builtin_amdgcn_exp2f(x)
#else
#define EXP2F(x) exp2f(x)
#endif

__device__ __forceinline__ hpair u2p(uint32 u) { return __builtin_bit_cast(hpair, u); }
__device__ __forceinline__ uint32 packh2(float lo, float hi) {
    hpair p; p.x = (_Float16)lo; p.y = (_Float16)hi;
    return __builtin_bit_cast(uint32, p);
}

__device__ __forceinline__ void compute_weights(
    int wt, int l,
    const float* __restrict__ Wq, const float* __restrict__ bq,
    const float* __restrict__ Wk,
    const float* __restrict__ Wv, const float* __restrict__ bv,
    float (*Msh)[7], float* wsh, float* wvsh, float SC2)
{
    const float* wq = Wq + l * 7 * HID;
    const float* wk = Wk + l * 7 * HID;
    if (wt < 49) {
        int c = wt / 7, cp = wt % 7;
        float s = 0.f;
        #pragma unroll 8
        for (int d = 0; d < HID; ++d) s = fmaf(wq[c * HID + d], wk[cp * HID + d], s);
        Msh[c][cp] = s * SC2;
    } else if (wt < 56) {
        int cp = wt - 49;
        float s = 0.f;
        #pragma unroll 8
        for (int d = 0; d < HID; ++d) s = fmaf(bq[l * HID + d], wk[cp * HID + d], s);
        wsh[cp] = s * SC2;
    } else if (wt < 63) {
        wvsh[wt - 56] = Wv[l * 7 + (wt - 56)];
    } else if (wt == 63) {
        wvsh[7] = bv[l];
    }
}

// 512 threads = 8 waves. Lane-quad owns 2 query rows: row0 = tid>>2, row1 = row0+128;
// jq = tid&3 picks a j-quarter. One ds_read_b128 per iter serves 2 rows; v lives in
// the h-row's 8th fp16 slot (nulled in the score by t3.y = 0). Quad-reduce = 2 shfl_xor.
__global__ __launch_bounds__(512, 4) void mlra_kernel(
    const float* __restrict__ power,
    const int*   __restrict__ ele_idx,
    const int*   __restrict__ azi_idx,
    const float* __restrict__ ele_emb,
    const float* __restrict__ azi_emb,
    const float* __restrict__ Wq,
    const float* __restrict__ bq,
    const float* __restrict__ Wk,
    const float* __restrict__ bk,
    const float* __restrict__ Wv,
    const float* __restrict__ bv,
    float* __restrict__ out)
{
    __shared__ uint4 hh[256];        // 8 fp16/row: (h0,h1)(h2,h3)(h4,h5)(h6,v); pads zero
    __shared__ float hrowf[256][9];  // fp32 h rows for t-phase (stride 9 -> conflict-free)
    __shared__ float Msh[2][7][7];   // both layers' folded SC2*Wq Wk^T
    __shared__ float wsh[2][7];
    __shared__ float wvsh[2][8];

    uint32* hhU = reinterpret_cast<uint32*>(hh);

    const int r    = blockIdx.x;
    const int tid  = threadIdx.x;
    const int row0 = tid >> 2;        // 0..127
    const int row1 = row0 + 128;      // 128..255
    const int jq   = tid & 3;

    const float SC2 = 0.17677669529663687f * 1.4426950408889634f;

    // ---- prologue: h build (threads 0-255) || both layers' weights (waves 4,5) ----
    if (tid < 256) {
        float hv[8];
        if (tid < KK) {
            int g = r * KK + tid;
            hv[0] = power[g];
            int ei = ele_idx[g];
            int ai = azi_idx[g];
            hv[1] = ele_emb[ei * 3 + 0];
            hv[2] = ele_emb[ei * 3 + 1];
            hv[3] = ele_emb[ei * 3 + 2];
            hv[4] = azi_emb[ai * 3 + 0];
            hv[5] = azi_emb[ai * 3 + 1];
            hv[6] = azi_emb[ai * 3 + 2];
            hv[7] = 0.f;
        } else {
            #pragma unroll
            for (int c = 0; c < 8; ++c) hv[c] = 0.f;
        }
        #pragma unroll
        for (int c = 0; c < 7; ++c) hrowf[tid][c] = hv[c];
        uint4 u;
        u.x = packh2(hv[0], hv[1]);
        u.y = packh2(hv[2], hv[3]);
        u.z = packh2(hv[4], hv[5]);
        u.w = packh2(hv[6], 0.f);    // v filled per layer in t-phase
        hh[tid] = u;
    } else if (tid < 384) {
        int l = (tid - 256) >> 6;    // wave 4 -> layer 0, wave 5 -> layer 1
        compute_weights(tid & 63, l, Wq, bq, Wk, Wv, bv, Msh[l], wsh[l], wvsh[l], SC2);
    }
    __syncthreads();   // (1) h + both layers' weights ready

    float x0 = 0.f, x1 = 0.f;

    for (int l = 0; l < 2; ++l) {
        // ---- t-phase: 2 rows per thread; jq==0 computes v and stores into hh.w ----
        float hv0[7], hv1[7];
        #pragma unroll
        for (int c = 0; c < 7; ++c) { hv0[c] = hrowf[row0][c]; hv1[c] = hrowf[row1][c]; }
        float tt0[7], tt1[7];
        #pragma unroll
        for (int cp = 0; cp < 7; ++cp) {
            float s0 = wsh[l][cp], s1 = wsh[l][cp];
            #pragma unroll
            for (int c = 0; c < 7; ++c) {
                float m = Msh[l][c][cp];
                s0 = fmaf(hv0[c], m, s0);
                s1 = fmaf(hv1[c], m, s1);
            }
            tt0[cp] = s0; tt1[cp] = s1;
        }
        hpair t0a = u2p(packh2(tt0[0], tt0[1]));
        hpair t0b = u2p(packh2(tt0[2], tt0[3]));
        hpair t0c = u2p(packh2(tt0[4], tt0[5]));
        hpair t0d = u2p(packh2(tt0[6], 0.f));   // .y = 0 nullifies the v slot
        hpair t1a = u2p(packh2(tt1[0], tt1[1]));
        hpair t1b = u2p(packh2(tt1[2], tt1[3]));
        hpair t1c = u2p(packh2(tt1[4], tt1[5]));
        hpair t1d = u2p(packh2(tt1[6], 0.f));
        if (jq == 0) {
            float v0 = wvsh[l][7], v1 = wvsh[l][7];
            #pragma unroll
            for (int c = 0; c < 7; ++c) {
                v0 = fmaf(hv0[c], wvsh[l][c], v0);
                v1 = fmaf(hv1[c], wvsh[l][c], v1);
            }
            hhU[row0 * 4 + 3] = packh2(hv0[6], v0);            // row0 < KK always
            if (row1 < KK) hhU[row1 * 4 + 3] = packh2(hv1[6], v1);
        }
        __syncthreads();   // (2/5) v ready

        // ---- inner: 64 iters over this quad's j-quarter, 2 rows per iter ----
        float ss0 = 0.f, oo0 = 0.f, ss1 = 0.f, oo1 = 0.f;
        #pragma unroll 8
        for (int it = 0; it < 64; ++it) {
            const int j = (it << 2) | jq;
            uint4 ua = hh[j];            // 4 distinct addrs/wave, 64B apart-contiguous
            float vj = (float)u2p(ua.w).y;
            float sc0 = FDOT2(u2p(ua.x), t0a,
                        FDOT2(u2p(ua.y), t0b,
                        FDOT2(u2p(ua.z), t0c,
                        FDOT2(u2p(ua.w), t0d, 0.f))));
            float sc1 = FDOT2(u2p(ua.x), t1a,
                        FDOT2(u2p(ua.y), t1b,
                        FDOT2(u2p(ua.z), t1c,
                        FDOT2(u2p(ua.w), t1d, 0.f))));
            float p0 = EXP2F(sc0);
            float p1 = EXP2F(sc1);
            ss0 += p0; oo0 = fmaf(p0, vj, oo0);
            ss1 += p1; oo1 = fmaf(p1, vj, oo1);
        }
        // pad rows 250..255 (zeroed): jq 0,1 visit 1 pad; jq 2,3 visit 2 (p=1, v=0)
        const float corr = 1.0f + (float)(jq >> 1);
        ss0 -= corr; ss1 -= corr;

        // ---- quad reduce (xor 1, then 2) ----
        ss0 += __shfl_xor(ss0, 1); ss0 += __shfl_xor(ss0, 2);
        oo0 += __shfl_xor(oo0, 1); oo0 += __shfl_xor(oo0, 2);
        ss1 += __shfl_xor(ss1, 1); ss1 += __shfl_xor(ss1, 2);
        oo1 += __shfl_xor(oo1, 1); oo1 += __shfl_xor(oo1, 2);
        x0 = oo0 / ss0;
        x1 = oo1 / ss1;

        if (l == 0) {
            __syncthreads();   // (3) all inner reads of hh done
            if (jq == 0) {
                hrowf[row0][0] = x0;                           // exact fp32 for L1 t-phase
                hhU[row0 * 4 + 0] = packh2(x0, hv0[1]);
                if (row1 < KK) {
                    hrowf[row1][0] = x1;
                    hhU[row1 * 4 + 0] = packh2(x1, hv1[1]);
                }
            }
            __syncthreads();   // (4) x-update published
        }
    }

    if (jq == 0) {
        out[r * KK + row0] = x0;
        if (row1 < KK) out[r * KK + row1] = x1;
    }
}

extern "C" void kernel_launch(void* const* d_in, const int* in_sizes, int n_in,
                              void* d_out, int out_size, void* d_ws, size_t ws_size,
                              hipStream_t stream) {
    const float* power   = (const float*)d_in[0];
    const int*   ele     = (const int*)d_in[1];
    const int*   azi     = (const int*)d_in[2];
    const float* ele_emb = (const float*)d_in[3];
    const float* azi_emb = (const float*)d_in[4];
    const float* Wq      = (const float*)d_in[5];
    const float* bq      = (const float*)d_in[6];
    const float* Wk      = (const float*)d_in[7];
    const float* bk      = (const float*)d_in[8];
    const float* Wv      = (const float*)d_in[9];
    const float* bv      = (const float*)d_in[10];
    float* outp = (float*)d_out;
    (void)bk;

    hipLaunchKernelGGL(mlra_kernel, dim3(NR), dim3(512), 0, stream,
                       power, ele, azi, ele_emb, azi_emb, Wq, bq, Wk, bk, Wv, bv, outp);
}